// Round 2
// baseline (115.004 us; speedup 1.0000x reference)
//
#include <hip/hip_runtime.h>

// SignedDistance: B=1, F=20908, Q=1e6.
// Outputs concatenated flat (float32):
//   [0,Q)      signed_distances
//   [Q,4Q)     residual_norm  (Q x 3)
//   [4Q,7Q)    closest_points (Q x 3)
//   [7Q,8Q)    closest_faces  (as float values)
//   [8Q,11Q)   clipped bcs    (Q x 3)
//
// 4 points per thread: all streaming loads/stores are 16B-aligned float4/int4.
// Nontemporal hints on streaming traffic keep the ~1MB gather tables (tri,
// fnorm) resident in per-XCD L2.

typedef float  vf4 __attribute__((ext_vector_type(4)));
typedef int    vi4 __attribute__((ext_vector_type(4)));

__device__ __forceinline__ vf4 ntload4(const float* p) {
    return __builtin_nontemporal_load((const vf4*)p);
}
__device__ __forceinline__ void ntstore4(float* p, vf4 v) {
    __builtin_nontemporal_store(v, (vf4*)p);
}

__global__ __launch_bounds__(256)
void SignedDistance_57698590655052_kernel(
    const float* __restrict__ tri,      // (F,3,3) flat
    const float* __restrict__ fnorm,    // (F,3) flat
    const float* __restrict__ pts,      // (Q,3) flat
    const int*   __restrict__ faces,    // (Q,)
    const float* __restrict__ bcs_in,   // (Q,3) flat
    float* __restrict__ out,
    int Q)
{
    int t  = blockIdx.x * blockDim.x + threadIdx.x;
    int q0 = t * 4;
    if (q0 >= Q) return;

    float* sd_out = out;
    float* rn_out = out + (size_t)Q;
    float* cp_out = out + (size_t)4 * Q;
    float* fc_out = out + (size_t)7 * Q;
    float* bc_out = out + (size_t)8 * Q;

    if (q0 + 3 < Q) {
        // ---- vector path: 4 points ----
        vf4 pA = ntload4(pts + 3*q0 + 0);
        vf4 pB = ntload4(pts + 3*q0 + 4);
        vf4 pC = ntload4(pts + 3*q0 + 8);
        vf4 bA = ntload4(bcs_in + 3*q0 + 0);
        vf4 bB = ntload4(bcs_in + 3*q0 + 4);
        vf4 bC = ntload4(bcs_in + 3*q0 + 8);
        vi4 f4 = __builtin_nontemporal_load((const vi4*)(faces + q0));

        float pf[12] = {pA.x,pA.y,pA.z,pA.w, pB.x,pB.y,pB.z,pB.w, pC.x,pC.y,pC.z,pC.w};
        float bf[12] = {bA.x,bA.y,bA.z,bA.w, bB.x,bB.y,bB.z,bB.w, bC.x,bC.y,bC.z,bC.w};
        int   fi[4]  = {f4.x, f4.y, f4.z, f4.w};

        float sd[4], fcf[4], rn[12], cp[12], bc[12];

        #pragma unroll
        for (int i = 0; i < 4; ++i) {
            int face = fi[i];
            float b0 = fminf(fmaxf(bf[3*i+0], 0.0f), 1.0f);
            float b1 = fminf(fmaxf(bf[3*i+1], 0.0f), 1.0f);
            float b2 = fminf(fmaxf(bf[3*i+2], 0.0f), 1.0f);

            const float* tt = tri + 9 * face;
            float cp0 = tt[0]*b0 + tt[3]*b1 + tt[6]*b2;
            float cp1 = tt[1]*b0 + tt[4]*b1 + tt[7]*b2;
            float cp2 = tt[2]*b0 + tt[5]*b1 + tt[8]*b2;

            float r0 = cp0 - pf[3*i+0];
            float r1 = cp1 - pf[3*i+1];
            float r2 = cp2 - pf[3*i+2];

            float ss   = r0*r0 + r1*r1 + r2*r2;
            float dist = sqrtf(ss);
            float nrm  = (dist == 0.0f) ? 1.0f : dist;
            float inv  = 1.0f / nrm;

            float rn0 = r0*inv, rn1 = r1*inv, rn2 = r2*inv;

            const float* nn = fnorm + 3 * face;
            float dp   = rn0*nn[0] + rn1*nn[1] + rn2*nn[2];
            float sign = (dp > 0.0f) ? -1.0f : 1.0f;

            sd[i]  = sign * dist;
            fcf[i] = (float)face;
            rn[3*i+0] = rn0; rn[3*i+1] = rn1; rn[3*i+2] = rn2;
            cp[3*i+0] = cp0; cp[3*i+1] = cp1; cp[3*i+2] = cp2;
            bc[3*i+0] = b0;  bc[3*i+1] = b1;  bc[3*i+2] = b2;
        }

        ntstore4(sd_out + q0, (vf4){sd[0], sd[1], sd[2], sd[3]});
        ntstore4(fc_out + q0, (vf4){fcf[0], fcf[1], fcf[2], fcf[3]});
        ntstore4(rn_out + 3*q0 + 0, (vf4){rn[0], rn[1], rn[2],  rn[3]});
        ntstore4(rn_out + 3*q0 + 4, (vf4){rn[4], rn[5], rn[6],  rn[7]});
        ntstore4(rn_out + 3*q0 + 8, (vf4){rn[8], rn[9], rn[10], rn[11]});
        ntstore4(cp_out + 3*q0 + 0, (vf4){cp[0], cp[1], cp[2],  cp[3]});
        ntstore4(cp_out + 3*q0 + 4, (vf4){cp[4], cp[5], cp[6],  cp[7]});
        ntstore4(cp_out + 3*q0 + 8, (vf4){cp[8], cp[9], cp[10], cp[11]});
        ntstore4(bc_out + 3*q0 + 0, (vf4){bc[0], bc[1], bc[2],  bc[3]});
        ntstore4(bc_out + 3*q0 + 4, (vf4){bc[4], bc[5], bc[6],  bc[7]});
        ntstore4(bc_out + 3*q0 + 8, (vf4){bc[8], bc[9], bc[10], bc[11]});
    } else {
        // ---- scalar tail ----
        for (int q = q0; q < Q; ++q) {
            int face = faces[q];
            float b0 = fminf(fmaxf(bcs_in[3*q+0], 0.0f), 1.0f);
            float b1 = fminf(fmaxf(bcs_in[3*q+1], 0.0f), 1.0f);
            float b2 = fminf(fmaxf(bcs_in[3*q+2], 0.0f), 1.0f);

            const float* tt = tri + 9 * face;
            float cp0 = tt[0]*b0 + tt[3]*b1 + tt[6]*b2;
            float cp1 = tt[1]*b0 + tt[4]*b1 + tt[7]*b2;
            float cp2 = tt[2]*b0 + tt[5]*b1 + tt[8]*b2;

            float r0 = cp0 - pts[3*q+0];
            float r1 = cp1 - pts[3*q+1];
            float r2 = cp2 - pts[3*q+2];

            float ss   = r0*r0 + r1*r1 + r2*r2;
            float dist = sqrtf(ss);
            float nrm  = (dist == 0.0f) ? 1.0f : dist;
            float inv  = 1.0f / nrm;

            float rn0 = r0*inv, rn1 = r1*inv, rn2 = r2*inv;

            const float* nn = fnorm + 3 * face;
            float dp   = rn0*nn[0] + rn1*nn[1] + rn2*nn[2];
            float sign = (dp > 0.0f) ? -1.0f : 1.0f;

            sd_out[q] = sign * dist;
            fc_out[q] = (float)face;
            rn_out[3*q+0] = rn0; rn_out[3*q+1] = rn1; rn_out[3*q+2] = rn2;
            cp_out[3*q+0] = cp0; cp_out[3*q+1] = cp1; cp_out[3*q+2] = cp2;
            bc_out[3*q+0] = b0;  bc_out[3*q+1] = b1;  bc_out[3*q+2] = b2;
        }
    }
}

extern "C" void kernel_launch(void* const* d_in, const int* in_sizes, int n_in,
                              void* d_out, int out_size, void* d_ws, size_t ws_size,
                              hipStream_t stream) {
    const float* tri    = (const float*)d_in[0];  // (B,F,3,3)
    const float* fnorm  = (const float*)d_in[1];  // (B,F,3)
    const float* pts    = (const float*)d_in[2];  // (B,Q,3)
    const int*   faces  = (const int*)d_in[3];    // (B,Q)
    const float* bcs    = (const float*)d_in[4];  // (B,Q,3)

    int Q = in_sizes[3];  // B*Q with B=1

    int block = 256;
    int nthreads = (Q + 3) / 4;
    int grid  = (nthreads + block - 1) / block;
    SignedDistance_57698590655052_kernel<<<grid, block, 0, stream>>>(
        tri, fnorm, pts, faces, bcs, (float*)d_out, Q);
}

// Round 3
// 112.994 us; speedup vs baseline: 1.0178x; 1.0178x over previous
//
#include <hip/hip_runtime.h>

// SignedDistance: B=1, F=20908, Q=1e6.
// Outputs concatenated flat (float32):
//   [0,Q)      signed_distances
//   [Q,4Q)     residual_norm  (Q x 3)
//   [4Q,7Q)    closest_points (Q x 3)
//   [7Q,8Q)    closest_faces  (as float values)
//   [8Q,11Q)   clipped bcs    (Q x 3)
//
// 4 points/thread; all streaming traffic is dense 16B dwordx4.
// No private arrays (zero scratch-spill risk). Normal loads (L1/L2 path),
// nontemporal stores so 44MB of output doesn't evict the ~1MB gather tables.

typedef float  vf4 __attribute__((ext_vector_type(4)));
typedef int    vi4 __attribute__((ext_vector_type(4)));

__device__ __forceinline__ void ntstore4(float* p, vf4 v) {
    __builtin_nontemporal_store(v, (vf4*)p);
}

struct PtOut {
    float sd, rn0, rn1, rn2, cp0, cp1, cp2, b0, b1, b2, fc;
};

__device__ __forceinline__ PtOut compute_pt(
    const float* __restrict__ tri, const float* __restrict__ fnorm,
    int face, float p0, float p1, float p2,
    float bb0, float bb1, float bb2)
{
    PtOut o;
    float b0 = fminf(fmaxf(bb0, 0.0f), 1.0f);
    float b1 = fminf(fmaxf(bb1, 0.0f), 1.0f);
    float b2 = fminf(fmaxf(bb2, 0.0f), 1.0f);

    const float* t = tri + 9 * face;
    float cp0 = t[0]*b0 + t[3]*b1 + t[6]*b2;
    float cp1 = t[1]*b0 + t[4]*b1 + t[7]*b2;
    float cp2 = t[2]*b0 + t[5]*b1 + t[8]*b2;

    float r0 = cp0 - p0;
    float r1 = cp1 - p1;
    float r2 = cp2 - p2;

    float ss   = r0*r0 + r1*r1 + r2*r2;
    float dist = sqrtf(ss);
    float nrm  = (dist == 0.0f) ? 1.0f : dist;
    float inv  = 1.0f / nrm;

    float rn0 = r0*inv, rn1 = r1*inv, rn2 = r2*inv;

    const float* nn = fnorm + 3 * face;
    float dp   = rn0*nn[0] + rn1*nn[1] + rn2*nn[2];
    float sign = (dp > 0.0f) ? -1.0f : 1.0f;

    o.sd = sign * dist;
    o.rn0 = rn0; o.rn1 = rn1; o.rn2 = rn2;
    o.cp0 = cp0; o.cp1 = cp1; o.cp2 = cp2;
    o.b0 = b0;  o.b1 = b1;  o.b2 = b2;
    o.fc = (float)face;
    return o;
}

__global__ __launch_bounds__(256)
void SignedDistance_57698590655052_kernel(
    const float* __restrict__ tri,      // (F,3,3) flat
    const float* __restrict__ fnorm,    // (F,3) flat
    const float* __restrict__ pts,      // (Q,3) flat
    const int*   __restrict__ faces,    // (Q,)
    const float* __restrict__ bcs_in,   // (Q,3) flat
    float* __restrict__ out,
    int Q)
{
    int t  = blockIdx.x * blockDim.x + threadIdx.x;
    int q0 = t * 4;
    if (q0 >= Q) return;

    float* sd_out = out;
    float* rn_out = out + (size_t)Q;
    float* cp_out = out + (size_t)4 * Q;
    float* fc_out = out + (size_t)7 * Q;
    float* bc_out = out + (size_t)8 * Q;

    if (q0 + 3 < Q) {
        // ---- vector path: 4 points, all dense dwordx4 ----
        vf4 pA = *(const vf4*)(pts + 3*q0 + 0);
        vf4 pB = *(const vf4*)(pts + 3*q0 + 4);
        vf4 pC = *(const vf4*)(pts + 3*q0 + 8);
        vf4 bA = *(const vf4*)(bcs_in + 3*q0 + 0);
        vf4 bB = *(const vf4*)(bcs_in + 3*q0 + 4);
        vf4 bC = *(const vf4*)(bcs_in + 3*q0 + 8);
        vi4 f4 = *(const vi4*)(faces + q0);

        PtOut o0 = compute_pt(tri, fnorm, f4.x, pA.x, pA.y, pA.z, bA.x, bA.y, bA.z);
        PtOut o1 = compute_pt(tri, fnorm, f4.y, pA.w, pB.x, pB.y, bA.w, bB.x, bB.y);
        PtOut o2 = compute_pt(tri, fnorm, f4.z, pB.z, pB.w, pC.x, bB.z, bB.w, bC.x);
        PtOut o3 = compute_pt(tri, fnorm, f4.w, pC.y, pC.z, pC.w, bC.y, bC.z, bC.w);

        ntstore4(sd_out + q0, (vf4){o0.sd, o1.sd, o2.sd, o3.sd});
        ntstore4(fc_out + q0, (vf4){o0.fc, o1.fc, o2.fc, o3.fc});

        ntstore4(rn_out + 3*q0 + 0, (vf4){o0.rn0, o0.rn1, o0.rn2, o1.rn0});
        ntstore4(rn_out + 3*q0 + 4, (vf4){o1.rn1, o1.rn2, o2.rn0, o2.rn1});
        ntstore4(rn_out + 3*q0 + 8, (vf4){o2.rn2, o3.rn0, o3.rn1, o3.rn2});

        ntstore4(cp_out + 3*q0 + 0, (vf4){o0.cp0, o0.cp1, o0.cp2, o1.cp0});
        ntstore4(cp_out + 3*q0 + 4, (vf4){o1.cp1, o1.cp2, o2.cp0, o2.cp1});
        ntstore4(cp_out + 3*q0 + 8, (vf4){o2.cp2, o3.cp0, o3.cp1, o3.cp2});

        ntstore4(bc_out + 3*q0 + 0, (vf4){o0.b0, o0.b1, o0.b2, o1.b0});
        ntstore4(bc_out + 3*q0 + 4, (vf4){o1.b1, o1.b2, o2.b0, o2.b1});
        ntstore4(bc_out + 3*q0 + 8, (vf4){o2.b2, o3.b0, o3.b1, o3.b2});
    } else {
        // ---- scalar tail ----
        for (int q = q0; q < Q; ++q) {
            PtOut o = compute_pt(tri, fnorm, faces[q],
                                 pts[3*q+0], pts[3*q+1], pts[3*q+2],
                                 bcs_in[3*q+0], bcs_in[3*q+1], bcs_in[3*q+2]);
            sd_out[q] = o.sd;
            fc_out[q] = o.fc;
            rn_out[3*q+0] = o.rn0; rn_out[3*q+1] = o.rn1; rn_out[3*q+2] = o.rn2;
            cp_out[3*q+0] = o.cp0; cp_out[3*q+1] = o.cp1; cp_out[3*q+2] = o.cp2;
            bc_out[3*q+0] = o.b0;  bc_out[3*q+1] = o.b1;  bc_out[3*q+2] = o.b2;
        }
    }
}

extern "C" void kernel_launch(void* const* d_in, const int* in_sizes, int n_in,
                              void* d_out, int out_size, void* d_ws, size_t ws_size,
                              hipStream_t stream) {
    const float* tri    = (const float*)d_in[0];  // (B,F,3,3)
    const float* fnorm  = (const float*)d_in[1];  // (B,F,3)
    const float* pts    = (const float*)d_in[2];  // (B,Q,3)
    const int*   faces  = (const int*)d_in[3];    // (B,Q)
    const float* bcs    = (const float*)d_in[4];  // (B,Q,3)

    int Q = in_sizes[3];  // B*Q with B=1

    int block = 256;
    int nthreads = (Q + 3) / 4;
    int grid  = (nthreads + block - 1) / block;
    SignedDistance_57698590655052_kernel<<<grid, block, 0, stream>>>(
        tri, fnorm, pts, faces, bcs, (float*)d_out, Q);
}

// Round 4
// 104.934 us; speedup vs baseline: 1.0960x; 1.0768x over previous
//
#include <hip/hip_runtime.h>

// SignedDistance: B=1, F=20908, Q=1e6.
// Outputs concatenated flat (float32):
//   [0,Q)      signed_distances
//   [Q,4Q)     residual_norm  (Q x 3)
//   [4Q,7Q)    closest_points (Q x 3)
//   [7Q,8Q)    closest_faces  (as float values)
//   [8Q,11Q)   clipped bcs    (Q x 3)
//
// R4 = revert to R1 scalar form (best measured: 106.7 vs 115.0/113.0 for the
// vectorized variants). Evidence from rounds 1-3: kernel device time < 42 us
// in all variants (never appears in rocprof top-5; all slots are harness
// poison fills at ~78% HBM peak), and bench dur_us is dominated by a fixed
// ~90 us harness floor (re-poison fills + input restores). Stride-12 scalar
// accesses are fully coalescible across the wave (every byte of the wave's
// footprint is touched), so this is within noise of the 72 MB / 6.3 TB/s
// traffic roofline anyway.

__global__ __launch_bounds__(256)
void SignedDistance_57698590655052_kernel(
    const float* __restrict__ tri,      // (F,3,3) flat
    const float* __restrict__ fnorm,    // (F,3) flat
    const float* __restrict__ pts,      // (Q,3) flat
    const int*   __restrict__ faces,    // (Q,)
    const float* __restrict__ bcs_in,   // (Q,3) flat
    float* __restrict__ out,
    int Q)
{
    int q = blockIdx.x * blockDim.x + threadIdx.x;
    if (q >= Q) return;

    int face = faces[q];

    // clip bcs to [0,1]
    float b0 = fminf(fmaxf(bcs_in[3*q + 0], 0.0f), 1.0f);
    float b1 = fminf(fmaxf(bcs_in[3*q + 1], 0.0f), 1.0f);
    float b2 = fminf(fmaxf(bcs_in[3*q + 2], 0.0f), 1.0f);

    // gather triangle (v,c) flat = v*3+c ; cp[c] = sum_v tri[v][c]*bc[v]
    const float* t = tri + 9 * face;
    float t00 = t[0], t01 = t[1], t02 = t[2];
    float t10 = t[3], t11 = t[4], t12 = t[5];
    float t20 = t[6], t21 = t[7], t22 = t[8];

    float cp0 = t00 * b0 + t10 * b1 + t20 * b2;
    float cp1 = t01 * b0 + t11 * b1 + t21 * b2;
    float cp2 = t02 * b0 + t12 * b1 + t22 * b2;

    float p0 = pts[3*q + 0];
    float p1 = pts[3*q + 1];
    float p2 = pts[3*q + 2];

    float r0 = cp0 - p0;
    float r1 = cp1 - p1;
    float r2 = cp2 - p2;

    float ss   = r0*r0 + r1*r1 + r2*r2;
    float dist = sqrtf(ss);
    float nrm  = (dist == 0.0f) ? 1.0f : dist;
    float inv  = 1.0f / nrm;

    float rn0 = r0 * inv;
    float rn1 = r1 * inv;
    float rn2 = r2 * inv;

    float n0 = fnorm[3*face + 0];
    float n1 = fnorm[3*face + 1];
    float n2 = fnorm[3*face + 2];

    float dp   = rn0*n0 + rn1*n1 + rn2*n2;
    float sign = (dp > 0.0f) ? -1.0f : 1.0f;

    // writes
    out[q] = sign * dist;

    float* rn_out = out + (size_t)Q;
    rn_out[3*q + 0] = rn0;
    rn_out[3*q + 1] = rn1;
    rn_out[3*q + 2] = rn2;

    float* cp_out = out + (size_t)4 * Q;
    cp_out[3*q + 0] = cp0;
    cp_out[3*q + 1] = cp1;
    cp_out[3*q + 2] = cp2;

    out[(size_t)7 * Q + q] = (float)face;

    float* bc_out = out + (size_t)8 * Q;
    bc_out[3*q + 0] = b0;
    bc_out[3*q + 1] = b1;
    bc_out[3*q + 2] = b2;
}

extern "C" void kernel_launch(void* const* d_in, const int* in_sizes, int n_in,
                              void* d_out, int out_size, void* d_ws, size_t ws_size,
                              hipStream_t stream) {
    const float* tri    = (const float*)d_in[0];  // (B,F,3,3)
    const float* fnorm  = (const float*)d_in[1];  // (B,F,3)
    const float* pts    = (const float*)d_in[2];  // (B,Q,3)
    const int*   faces  = (const int*)d_in[3];    // (B,Q)
    const float* bcs    = (const float*)d_in[4];  // (B,Q,3)

    int Q = in_sizes[3];  // B*Q with B=1

    int block = 256;
    int grid  = (Q + block - 1) / block;
    SignedDistance_57698590655052_kernel<<<grid, block, 0, stream>>>(
        tri, fnorm, pts, faces, bcs, (float*)d_out, Q);
}